// Round 3
// baseline (725.332 us; speedup 1.0000x reference)
//
#include <hip/hip_runtime.h>

// ---- types ----
typedef __bf16 bf16x8 __attribute__((ext_vector_type(8)));
typedef float  floatx4 __attribute__((ext_vector_type(4)));
typedef float  fvec4  __attribute__((ext_vector_type(4)));
typedef unsigned short ushort4v __attribute__((ext_vector_type(4)));
typedef unsigned short ushort8v __attribute__((ext_vector_type(8)));

__device__ __forceinline__ unsigned short f2bf(float f) {
  unsigned int u = __float_as_uint(f);
  u = u + 0x7FFFu + ((u >> 16) & 1u);   // RNE
  return (unsigned short)(u >> 16);
}

// ws layout:
//   0        : WP2 bf16 [29][256][512]
//   WP3_OFF  : WP3 bf16 [2][256][768]
//   X0_OFF   : X0 bf16 [16*256][128]; then X1 (p120), X2 (p120), X3 (p56)
//   32 MiB   : tbl u16 [16384]  (assemble index table)
//   64 MiB   : Y fp32 [31][16*256][128]
#define WP3_OFF   3801088    // ushort elems
#define X0_OFF    4194304    // ushort elems
#define TBL_OFF_B (32u << 20)
#define Y_OFF_B   (64u << 20)

// ---- prep: fp32 -> bf16 copies (w2, w3, x0). Layout [o][i][k] == MFMA-B row order.
__global__ __launch_bounds__(256) void prep_kernel(
    const float* __restrict__ w2, const float* __restrict__ w3,
    const float* __restrict__ x, unsigned short* __restrict__ ws)
{
  int g = blockIdx.x * 256 + threadIdx.x;
  const float* src; unsigned short* dst;
  if (g < 950272)            { src = w2; dst = ws; }
  else if (g < 950272+98304) { g -= 950272; src = w3; dst = ws + WP3_OFF; }
  else                       { g -= (950272+98304); src = x; dst = ws + X0_OFF; }
  fvec4 v = *reinterpret_cast<const fvec4*>(src + 4*g);
  ushort4v o;
  o[0] = f2bf(v[0]); o[1] = f2bf(v[1]); o[2] = f2bf(v[2]); o[3] = f2bf(v[3]);
  *reinterpret_cast<ushort4v*>(dst + 4*g) = o;
}

// ---- index table for assemble: entry (r*128+c) -> S-index (layer*129+m or
// 31*129+r for diag) or 0xFFFF for structural zero.
__global__ __launch_bounds__(256) void tbl_kernel(unsigned short* __restrict__ tbl)
{
  const int g = blockIdx.x * 256 + threadIdx.x;   // 0..16383
  const int r = g >> 7, c = g & 127, d = c - r;
  unsigned short v = 0xFFFFu;
  if (d == 0) v = (unsigned short)(31 * 129 + r);
  else if (d >= 1 && d <= 15) v = (unsigned short)((d - 1) * 129 + r);
  else if (d >= 17 && d <= 31 && (d & 1) == 1 && (r & 1) == 0)
    v = (unsigned short)((15 + ((d - 17) >> 1)) * 129 + (r >> 1));
  else if (d >= 35 && d <= 63 && (d & 3) == 3 && (r & 3) == 0)
    v = (unsigned short)((23 + ((d - 35) >> 2)) * 129 + (r >> 2));
  tbl[g] = v;
}

// ---- fused conv group: NL layers in one kernel, halo recompute (no cross-block
// dependency). Block = (m-tile g, batch b), 512 threads = 8 waves, each wave owns
// 32 output channels. Packed A-matrices double-buffered in LDS; layer j output
// window W_j = TW + NL-1-j rows starting at t0 = g*TW (shared coords; halo
// overlap between blocks recomputes bit-identical values -> benign double Y
// writes). Garbage beyond real Lout provably feeds only discarded outputs.
template<int NL, int KW0, int TW, int LPIN, int LOUT0, int LPOUT, bool XOUT>
__global__ __launch_bounds__(512, 2) void fused_group(
    const unsigned short* __restrict__ Xin,
    unsigned short* __restrict__ Xout,
    const unsigned short* __restrict__ W2base,   // layer j (k2) at + (j-K3)*131072
    const unsigned short* __restrict__ W3,       // k3 weights (KW0==3 only)
    const float* __restrict__ B2base,
    const float* __restrict__ B3,
    float* __restrict__ Ybase)                   // Y slice for layer 0 of group
{
  constexpr int K3   = (KW0 == 3) ? 1 : 0;
  constexpr int W0   = TW + NL - 1;
  constexpr int R0   = ((W0 + 15) / 16) * 16;
  constexpr int R1   = ((W0 - 1 + 15) / 16) * 16;
  constexpr int P0   = (KW0 == 3) ? 776 : 520;
  constexpr int LDSA = P0 * R0;
  constexpr int LDSB = 520 * R1;
  __shared__ unsigned short LA[LDSA + LDSB];

  const int tid = threadIdx.x;
  const int g = blockIdx.x, b = blockIdx.y;
  const int t0 = g * TW;

  // ---- stage layer-0 packed A from global bf16 activations ----
  {
    const int i = tid & 255, h = tid >> 8;
    constexpr int SPAN = (KW0 == 3) ? (2 * W0 + 1) : (W0 + 1);
    constexpr int NV = (SPAN + 7) / 8;
    constexpr int HR = (W0 + 1) / 2;
    const unsigned short* rp = Xin + (b * 256 + i) * LPIN + ((KW0 == 3) ? 2 * t0 : t0);
    ushort8v xr[NV];
#pragma unroll
    for (int v = 0; v < NV; ++v) xr[v] = *reinterpret_cast<const ushort8v*>(rp + v * 8);
    const unsigned short* xs = reinterpret_cast<const unsigned short*>(xr);
#pragma unroll
    for (int rr = 0; rr < HR; ++rr) {
      const int r = h * HR + rr;
      if (r < W0) {
        if (KW0 == 2) {
          unsigned int pk = (unsigned int)xs[r] | ((unsigned int)xs[r + 1] << 16);
          *reinterpret_cast<unsigned int*>(&LA[r * 520 + 2 * i]) = pk;
        } else {
          const int base = r * 776 + 3 * i;
          LA[base]     = xs[2 * r];
          LA[base + 1] = xs[2 * r + 1];
          LA[base + 2] = xs[2 * r + 2];
        }
      }
    }
  }
  __syncthreads();

  const int wave = tid >> 6, lane = tid & 63;
  const int l15 = lane & 15, quad = lane >> 4;
  const int nA = wave * 32 + l15, nB = nA + 16;

#pragma unroll 1
  for (int j = 0; j < NL; ++j) {
    const int  Wj   = TW + NL - 1 - j;
    const int  MTH  = (Wj + 15) >> 4;
    const bool isK3 = (KW0 == 3) && (j == 0);
    const int  K    = isK3 ? 768 : 512;
    const int  NIT  = isK3 ? 24 : 16;
    const int  pit  = isK3 ? 776 : 520;
    const unsigned short* Wl = isK3 ? W3 : (W2base + (long)(j - K3) * 131072);
    const float* bl = isK3 ? B3 : (B2base + (j - K3) * 256);
    const unsigned short* src = LA + ((j & 1) ? LDSA : 0);
    unsigned short*       dst = LA + ((j & 1) ? 0 : LDSA);

    const unsigned short* wA = Wl + nA * K + quad * 8;
    const unsigned short* wB = Wl + nB * K + quad * 8;
    int ab[3];
#pragma unroll
    for (int t = 0; t < 3; ++t) ab[t] = (t * 16 + l15) * pit + quad * 8;

    floatx4 acc[2][3];
#pragma unroll
    for (int p = 0; p < 2; ++p)
#pragma unroll
      for (int t = 0; t < 3; ++t) acc[p][t] = (floatx4){0.f, 0.f, 0.f, 0.f};

#pragma unroll 4
    for (int kc = 0; kc < NIT; ++kc) {
      bf16x8 bA = *reinterpret_cast<const bf16x8*>(wA + kc * 32);
      bf16x8 bB = *reinterpret_cast<const bf16x8*>(wB + kc * 32);
#pragma unroll
      for (int t = 0; t < 3; ++t) {
        if (t < MTH) {
          bf16x8 a = *reinterpret_cast<const bf16x8*>(&src[ab[t] + kc * 32]);
          acc[0][t] = __builtin_amdgcn_mfma_f32_16x16x32_bf16(a, bA, acc[0][t], 0, 0, 0);
          acc[1][t] = __builtin_amdgcn_mfma_f32_16x16x32_bf16(a, bB, acc[1][t], 0, 0, 0);
        }
      }
    }

    // ---- epilogue: bias, Y fp32, pack next layer's A (k2) into other buffer
    const float bvA = bl[nA], bvB = bl[nB];
    const int Wn = Wj - 1;              // next layer's window (j<NL-1)
    const int Lout = LOUT0 - j;
#pragma unroll
    for (int p = 0; p < 2; ++p) {
      const int n = p ? nB : nA;
      const float bv = p ? bvB : bvA;
      float* yr = Ybase + (long)j * 524288 + (b * 256 + n) * 128;
      unsigned short* xo = XOUT ? (Xout + (b * 256 + n) * LPOUT) : (unsigned short*)0;
#pragma unroll
      for (int t = 0; t < 3; ++t) {
        if (t < MTH) {
#pragma unroll
          for (int r = 0; r < 4; ++r) {
            const int ro = t * 16 + quad * 4 + r;
            const float v = acc[p][t][r] + bv;
            const unsigned short bf = f2bf(v);
            if (j < NL - 1) {
              if (ro < Wn)            dst[ro * 520 + 2 * n]       = bf;
              if (ro >= 1 && ro <= Wn) dst[(ro - 1) * 520 + 2 * n + 1] = bf;
            }
            const int m = t0 + ro;
            if (ro < Wj && m < Lout) {
              yr[m] = v;
              if (XOUT && j == NL - 1) xo[m] = bf;
            }
          }
        }
      }
    }
    __syncthreads();
  }
}

// ---- assemble v3: per-(b,ch) block; stage stripe runs + diag row into LDS
// (pitch 129), then emit the 64KB tile coalesced via the precomputed u16 table.
__global__ __launch_bounds__(256) void assemble_kernel(
    float* __restrict__ out, const float* __restrict__ x,
    const unsigned short* __restrict__ tbl, const float* __restrict__ Y)
{
  __shared__ float S[32 * 129];
  const int blk = blockIdx.x;        // 0..4095 == b*256+ch
  const int tid = threadIdx.x;

  {
    const int m = tid & 127, half = tid >> 7;   // two layers staged per pass
#pragma unroll
    for (int lp = 0; lp < 16; ++lp) {
      const int l = lp * 2 + half;
      if (l < 31) {
        const int Lout = (l < 15) ? (127 - l)
                       : (l == 15) ? 56
                       : (l < 23)  ? (71 - l)
                       : (l == 23) ? 24 : (47 - l);
        if (m < Lout) S[l * 129 + m] = Y[(long)l * 524288 + blk * 128 + m];
      } else {
        S[31 * 129 + m] = x[blk * 128 + m];
      }
    }
  }
  __syncthreads();

  const long obase = (long)blk << 14;
#pragma unroll 1
  for (int it = 0; it < 16; ++it) {
    const int flat = it * 256 + tid;          // fvec4 index in the 128x128 tile
    ushort4v t4 = *reinterpret_cast<const ushort4v*>(tbl + 4 * flat);
    fvec4 v;
#pragma unroll
    for (int jj = 0; jj < 4; ++jj) {
      const unsigned short t = t4[jj];
      const int idx = (t == 0xFFFFu) ? 0 : (int)t;
      const float sv = S[idx];
      v[jj] = (t == 0xFFFFu) ? 0.f : sv;
    }
    *reinterpret_cast<fvec4*>(out + obase + 4 * flat) = v;
  }
}

extern "C" void kernel_launch(void* const* d_in, const int* in_sizes, int n_in,
                              void* d_out, int out_size, void* d_ws, size_t ws_size,
                              hipStream_t stream)
{
  const float* x  = (const float*)d_in[0];
  const float* w2 = (const float*)d_in[1];
  const float* b2 = (const float*)d_in[2];
  const float* w3 = (const float*)d_in[3];
  const float* b3 = (const float*)d_in[4];
  float* out = (float*)d_out;
  unsigned short* ws = (unsigned short*)d_ws;
  unsigned short* tbl = (unsigned short*)((char*)d_ws + TBL_OFF_B);
  float* Y = (float*)((char*)d_ws + Y_OFF_B);

  unsigned short* X0 = ws + X0_OFF;                 // pitch 128
  unsigned short* X1 = X0 + 524288 + 64;            // pitch 120 (L=120)
  unsigned short* X2 = X1 + 491520 + 64;            // pitch 120 (L=113)
  unsigned short* X3 = X2 + 491520 + 64;            // pitch 56  (L=49)

  prep_kernel<<<4608, 256, 0, stream>>>(w2, w3, x, ws);
  tbl_kernel<<<64, 256, 0, stream>>>(tbl);

  // layers 0..7   (8 x k2), L 128 -> 120
  fused_group<8, 2, 32, 128, 127, 120, true><<<dim3(4, 16), 512, 0, stream>>>(
      X0, X1, ws, (const unsigned short*)0, b2, (const float*)0, Y);
  // layers 8..14  (7 x k2), L 120 -> 113
  fused_group<7, 2, 32, 120, 119, 120, true><<<dim3(4, 16), 512, 0, stream>>>(
      X1, X2, ws + (long)8 * 131072, (const unsigned short*)0,
      b2 + 8 * 256, (const float*)0, Y + (long)8 * 524288);
  // layers 15..22 (k3 + 7 x k2), L 113 -> 56 -> 49
  fused_group<8, 3, 32, 120, 56, 56, true><<<dim3(2, 16), 512, 0, stream>>>(
      X2, X3, ws + (long)15 * 131072, ws + WP3_OFF,
      b2 + 15 * 256, b3, Y + (long)15 * 524288);
  // layers 23..30 (k3 + 7 x k2), L 49 -> 24 -> 17
  fused_group<8, 3, 17, 56, 24, 56, false><<<dim3(1, 16), 512, 0, stream>>>(
      X3, (unsigned short*)0, ws + (long)22 * 131072, ws + WP3_OFF + 196608,
      b2 + 22 * 256, b3 + 256, Y + (long)23 * 524288);

  assemble_kernel<<<4096, 256, 0, stream>>>(out, x, tbl, Y);
}

// Round 4
// 579.779 us; speedup vs baseline: 1.2511x; 1.2511x over previous
//
#include <hip/hip_runtime.h>

// ---- types ----
typedef __bf16 bf16x8 __attribute__((ext_vector_type(8)));
typedef float  floatx4 __attribute__((ext_vector_type(4)));
typedef float  fvec4  __attribute__((ext_vector_type(4)));
typedef unsigned short ushort4v __attribute__((ext_vector_type(4)));
typedef unsigned short ushort8v __attribute__((ext_vector_type(8)));

__device__ __forceinline__ unsigned short f2bf(float f) {
  unsigned int u = __float_as_uint(f);
  u = u + 0x7FFFu + ((u >> 16) & 1u);   // RNE
  return (unsigned short)(u >> 16);
}

// ws layout (byte offsets):
//   0        : WP2 bf16 [29][256][512]          (B-operand rows for plain convs)
//   7602176  : WP3 bf16 [2][256][768]
//   8388608  : X chain region (~12 MB used)
//   25165824 : WT2 bf16 [29][2][256 i][256 c]   (w2 transposed: A-operand for compose)
//   33554432 : tbl u16 [16384]
//   34603008 : WD2 bf16 [29][2][256 n][256 c]   (w2 de-interleaved: B-operand for compose)
//   42991616 : WT3 bf16 [2][3][256 i][256 c]
//   44040192 : CP3 bf16 [13][256][768]          (composed k3 weights)
//   50331648 : CP5 bf16 [2][256][1280]          (composed k5 s2 weights)
//   52428800 : beff fp32 [15][256]
//   64 MiB   : Y fp32 [31][16*256][128]
#define WP3_OFF    3801088    // ushort elems
#define X0_OFF     4194304    // ushort elems
#define WT2_OFF_B  25165824
#define TBL_OFF_B  33554432
#define WD2_OFF_B  34603008
#define WT3_OFF_B  42991616
#define CP3_OFF_B  44040192
#define CP5_OFF_B  50331648
#define BEFF_OFF_B 52428800
#define Y_OFF_B    (64u << 20)

// ---- prep: bf16 copies of WP2, WP3, X0 + de-interleaved WD2 planes.
__global__ __launch_bounds__(256) void prep_kernel(
    const float* __restrict__ w2, const float* __restrict__ w3,
    const float* __restrict__ x, unsigned short* __restrict__ ws)
{
  int g = blockIdx.x * 256 + threadIdx.x;          // 0 .. 2129919
  if (g < 1179648) {
    const float* src; unsigned short* dst;
    if (g < 950272)       { src = w2; dst = ws; }
    else if (g < 1048576) { g -= 950272; src = w3; dst = ws + WP3_OFF; }
    else                  { g -= 1048576; src = x; dst = ws + X0_OFF; }
    fvec4 v = *reinterpret_cast<const fvec4*>(src + 4 * g);
    ushort4v o;
    o[0] = f2bf(v[0]); o[1] = f2bf(v[1]); o[2] = f2bf(v[2]); o[3] = f2bf(v[3]);
    *reinterpret_cast<ushort4v*>(dst + 4 * g) = o;
  } else {
    const int h = g - 1179648;                     // 0 .. 950271 over w2
    const long f = (long)4 * h;                    // w2 flat float idx, a=0, c even
    fvec4 v = *reinterpret_cast<const fvec4*>(w2 + f);
    const int c = (int)((f >> 1) & 255);
    const int n = (int)((f >> 9) & 255);
    const int l = (int)(f >> 17);
    unsigned short* wd = ws + (WD2_OFF_B / 2);
    unsigned int p0 = (unsigned int)f2bf(v[0]) | ((unsigned int)f2bf(v[2]) << 16);
    unsigned int p1 = (unsigned int)f2bf(v[1]) | ((unsigned int)f2bf(v[3]) << 16);
    *reinterpret_cast<unsigned int*>(wd + ((l * 2 + 0) * 256 + n) * 256 + c) = p0;
    *reinterpret_cast<unsigned int*>(wd + ((l * 2 + 1) * 256 + n) * 256 + c) = p1;
  }
}

// ---- transposed weight copies (LDS tile transpose, coalesced both sides).
__global__ __launch_bounds__(256) void wt_kernel(
    const float* __restrict__ w2, const float* __restrict__ w3,
    unsigned short* __restrict__ ws)
{
  __shared__ unsigned short T[3 * 64 * 65];
  unsigned short* wt2 = ws + WT2_OFF_B / 2;
  unsigned short* wt3 = ws + WT3_OFF_B / 2;
  const int bid = blockIdx.x, tid = threadIdx.x;
  if (bid < 464) {                                  // WT2: [l][b][i][c] = w2[l][c][i][b]
    const int l = bid >> 4, t16 = bid & 15, it = t16 & 3, ct = t16 >> 2;
    const int cc = tid >> 2, q = tid & 3;
    const int c = ct * 64 + cc;
    const long rb = ((long)(l * 256 + c) * 256 + it * 64 + q * 16) * 2;
#pragma unroll
    for (int u2 = 0; u2 < 8; ++u2) {
      fvec4 v = *reinterpret_cast<const fvec4*>(w2 + rb + u2 * 4);
      const int il = q * 16 + u2 * 2;
      T[0 * 4160 + cc * 65 + il]     = f2bf(v[0]);
      T[1 * 4160 + cc * 65 + il]     = f2bf(v[1]);
      T[0 * 4160 + cc * 65 + il + 1] = f2bf(v[2]);
      T[1 * 4160 + cc * 65 + il + 1] = f2bf(v[3]);
    }
    __syncthreads();
    const int b = tid >> 7, rest = tid & 127, i_loc = rest >> 1, half = rest & 1;
    unsigned short* dp = wt2 + ((long)((l * 2 + b) * 256 + it * 64 + i_loc)) * 256
                             + ct * 64 + half * 32;
#pragma unroll
    for (int v8 = 0; v8 < 4; ++v8) {
      ushort8v o;
#pragma unroll
      for (int e = 0; e < 8; ++e) o[e] = T[b * 4160 + (half * 32 + v8 * 8 + e) * 65 + i_loc];
      *reinterpret_cast<ushort8v*>(dp + v8 * 8) = o;
    }
  } else {                                          // WT3: [g][t][i][c] = w3[g][c][i][t]
    const int u = bid - 464, g = u >> 4, t16 = u & 15, it = t16 & 3, ct = t16 >> 2;
    const int cc = tid >> 2, q = tid & 3;
    const int c = ct * 64 + cc;
    const long rb = ((long)(g * 256 + c) * 256 + it * 64 + q * 16) * 3;
#pragma unroll
    for (int u4 = 0; u4 < 4; ++u4) {
      fvec4 v0 = *reinterpret_cast<const fvec4*>(w3 + rb + u4 * 12);
      fvec4 v1 = *reinterpret_cast<const fvec4*>(w3 + rb + u4 * 12 + 4);
      fvec4 v2 = *reinterpret_cast<const fvec4*>(w3 + rb + u4 * 12 + 8);
      const int il = q * 16 + u4 * 4;
      float e[12] = {v0[0],v0[1],v0[2],v0[3],v1[0],v1[1],v1[2],v1[3],v2[0],v2[1],v2[2],v2[3]};
#pragma unroll
      for (int di = 0; di < 4; ++di)
#pragma unroll
        for (int tp = 0; tp < 3; ++tp)
          T[tp * 4160 + cc * 65 + il + di] = f2bf(e[di * 3 + tp]);
    }
    __syncthreads();
    if (tid < 192) {
      const int tp = tid >> 6, i_loc = tid & 63;
      unsigned short* dp = wt3 + ((long)((g * 3 + tp) * 256 + it * 64 + i_loc)) * 256 + ct * 64;
#pragma unroll
      for (int v8 = 0; v8 < 8; ++v8) {
        ushort8v o;
#pragma unroll
        for (int e2 = 0; e2 < 8; ++e2) o[e2] = T[tp * 4160 + (v8 * 8 + e2) * 65 + i_loc];
        *reinterpret_cast<ushort8v*>(dp + v8 * 8) = o;
      }
    }
  }
}

__device__ __forceinline__ int lA_of_unit(int u) {
  return (u < 7) ? 2 * u : (u < 10) ? 16 + 2 * (u - 7) : 23 + 2 * (u - 10);
}

// ---- composed bias: beff[u][n] = bB[n] + sum_c (WB[n,c,0]+WB[n,c,1]) * bA[c], fp32.
__global__ __launch_bounds__(256) void beff_kernel(
    const float* __restrict__ w2, const float* __restrict__ b2,
    const float* __restrict__ b3, float* __restrict__ beff)
{
  __shared__ float sb[256];
  const int u = blockIdx.x, n = threadIdx.x;
  int lB; const float* bA;
  if (u < 13) { const int lA = lA_of_unit(u); lB = lA + 1; bA = b2 + lA * 256; }
  else        { lB = (u == 13) ? 15 : 22;     bA = b3 + (u - 13) * 256; }
  sb[n] = bA[n];
  __syncthreads();
  const float* wr = w2 + ((long)(lB * 256 + n)) * 512;
  float acc = 0.f;
#pragma unroll 8
  for (int c = 0; c < 256; c += 2) {
    fvec4 v = *reinterpret_cast<const fvec4*>(wr + 2 * c);
    acc += (v[0] + v[1]) * sb[c] + (v[2] + v[3]) * sb[c + 1];
  }
  beff[u * 256 + n] = b2[lB * 256 + n] + acc;
}

// ---- weight composition via MFMA: P[n,i,k] = sum_c WB[n,c,a]*WA[c,i,b], k=a+b.
__global__ __launch_bounds__(256) void compose_kernel(unsigned short* __restrict__ ws)
{
  const unsigned short* wt2 = ws + WT2_OFF_B / 2;
  const unsigned short* wt3 = ws + WT3_OFF_B / 2;
  const unsigned short* wd2 = ws + WD2_OFF_B / 2;
  unsigned short* cp3 = ws + CP3_OFF_B / 2;
  unsigned short* cp5 = ws + CP5_OFF_B / 2;
  const int tid = threadIdx.x, bid = blockIdx.x;
  const int wave = tid >> 6, lane = tid & 63, l15 = lane & 15, quad = lane >> 4;
  if (bid < 208) {                                   // 13 k3 units x (4 i-tiles x 4 n-tiles)
    const int u = bid >> 4, t16 = bid & 15, iblk = t16 & 3, nblk = t16 >> 2;
    const int lA = lA_of_unit(u), lB = lA + 1;
    const int n = nblk * 64 + wave * 16 + l15;
    floatx4 acc[3][4];
#pragma unroll
    for (int k = 0; k < 3; ++k)
#pragma unroll
      for (int t = 0; t < 4; ++t) acc[k][t] = (floatx4){0.f, 0.f, 0.f, 0.f};
#pragma unroll
    for (int a = 0; a < 2; ++a) {
      const unsigned short* bp = wd2 + ((long)((lB * 2 + a) * 256 + n)) * 256 + quad * 8;
#pragma unroll
      for (int bb = 0; bb < 2; ++bb) {
        const int k = a + bb;
        const unsigned short* ap = wt2 + ((long)((lA * 2 + bb) * 256 + iblk * 64 + l15)) * 256 + quad * 8;
#pragma unroll
        for (int kc = 0; kc < 8; ++kc) {
          bf16x8 bf = *reinterpret_cast<const bf16x8*>(bp + kc * 32);
#pragma unroll
          for (int t = 0; t < 4; ++t) {
            bf16x8 af = *reinterpret_cast<const bf16x8*>(ap + t * 4096 + kc * 32);
            acc[k][t] = __builtin_amdgcn_mfma_f32_16x16x32_bf16(af, bf, acc[k][t], 0, 0, 0);
          }
        }
      }
    }
#pragma unroll
    for (int t = 0; t < 4; ++t)
#pragma unroll
      for (int r = 0; r < 4; ++r) {
        const int i = iblk * 64 + t * 16 + quad * 4 + r;
        unsigned short* op = cp3 + ((long)(u * 256 + n)) * 768 + i * 3;
        op[0] = f2bf(acc[0][t][r]); op[1] = f2bf(acc[1][t][r]); op[2] = f2bf(acc[2][t][r]);
      }
  } else {                                           // 2 k5 units x (8 i-tiles x 4 n-tiles)
    const int b2i = bid - 208, v = b2i >> 5, t32 = b2i & 31, iblk = t32 & 7, nblk = t32 >> 3;
    const int lB = v ? 22 : 15, g = v;
    const int n = nblk * 64 + wave * 16 + l15;
    floatx4 acc[5][2];
#pragma unroll
    for (int k = 0; k < 5; ++k)
#pragma unroll
      for (int t = 0; t < 2; ++t) acc[k][t] = (floatx4){0.f, 0.f, 0.f, 0.f};
#pragma unroll
    for (int a = 0; a < 2; ++a) {
      const unsigned short* bp = wd2 + ((long)((lB * 2 + a) * 256 + n)) * 256 + quad * 8;
#pragma unroll
      for (int t3 = 0; t3 < 3; ++t3) {
        const int tau = 2 * a + t3;
        const unsigned short* ap = wt3 + ((long)((g * 3 + t3) * 256 + iblk * 32 + l15)) * 256 + quad * 8;
#pragma unroll
        for (int kc = 0; kc < 8; ++kc) {
          bf16x8 bf = *reinterpret_cast<const bf16x8*>(bp + kc * 32);
#pragma unroll
          for (int t = 0; t < 2; ++t) {
            bf16x8 af = *reinterpret_cast<const bf16x8*>(ap + t * 4096 + kc * 32);
            acc[tau][t] = __builtin_amdgcn_mfma_f32_16x16x32_bf16(af, bf, acc[tau][t], 0, 0, 0);
          }
        }
      }
    }
#pragma unroll
    for (int t = 0; t < 2; ++t)
#pragma unroll
      for (int r = 0; r < 4; ++r) {
        const int i = iblk * 32 + t * 16 + quad * 4 + r;
        unsigned short* op = cp5 + ((long)(v * 256 + n)) * 1280 + i * 5;
#pragma unroll
        for (int k = 0; k < 5; ++k) op[k] = f2bf(acc[k][t][r]);
      }
  }
}

// ---- tbl for assemble (unchanged logic).
__global__ __launch_bounds__(256) void tbl_kernel(unsigned short* __restrict__ tbl)
{
  const int g = blockIdx.x * 256 + threadIdx.x;
  const int r = g >> 7, c = g & 127, d = c - r;
  unsigned short v = 0xFFFFu;
  if (d == 0) v = (unsigned short)(31 * 129 + r);
  else if (d >= 1 && d <= 15) v = (unsigned short)((d - 1) * 129 + r);
  else if (d >= 17 && d <= 31 && (d & 1) == 1 && (r & 1) == 0)
    v = (unsigned short)((15 + ((d - 17) >> 1)) * 129 + (r >> 1));
  else if (d >= 35 && d <= 63 && (d & 3) == 3 && (r & 3) == 0)
    v = (unsigned short)((23 + ((d - 35) >> 2)) * 129 + (r >> 2));
  tbl[g] = v;
}

// ---- generic sub-conv (round-2 structure, templated width/stride).
template<int KW, int CS>
__device__ __forceinline__ void conv_sub(
    const unsigned short* __restrict__ Xin, unsigned short* __restrict__ Xout,
    const unsigned short* __restrict__ WP, const float* __restrict__ bias,
    float* __restrict__ Yl, unsigned short* LA,
    int Lpin, int Lout, int Lpout, int b, int m0, int n0, int tid, bool writeX)
{
  constexpr int KS = 256 * KW, pitch = KS + 8;
  constexpr int NV = (CS * 31 + KW + 7) / 8;
  {
    const int i = tid;
    const unsigned short* rp = Xin + ((b * 256 + i) * Lpin) + CS * m0;
    ushort8v xr[NV];
#pragma unroll
    for (int v = 0; v < NV; ++v) xr[v] = *reinterpret_cast<const ushort8v*>(rp + v * 8);
    const unsigned short* xs = reinterpret_cast<const unsigned short*>(xr);
    if (KW == 2) {
#pragma unroll
      for (int m = 0; m < 32; ++m) {
        unsigned int pk = (unsigned int)xs[m] | ((unsigned int)xs[m + 1] << 16);
        *reinterpret_cast<unsigned int*>(&LA[m * pitch + 2 * i]) = pk;
      }
    } else {
#pragma unroll
      for (int m = 0; m < 32; ++m)
#pragma unroll
        for (int kk = 0; kk < KW; ++kk)
          LA[m * pitch + KW * i + kk] = xs[CS * m + kk];
    }
  }
  __syncthreads();
  const int wave = tid >> 6, lane = tid & 63, l15 = lane & 15, quad = lane >> 4;
  const int nn = n0 + wave * 16 + l15;
  const unsigned short* wrow = WP + (long)nn * KS + quad * 8;
  floatx4 acc0 = {0.f, 0.f, 0.f, 0.f};
  floatx4 acc1 = {0.f, 0.f, 0.f, 0.f};
#pragma unroll
  for (int kc = 0; kc < KS / 32; ++kc) {
    bf16x8 bfrag = *reinterpret_cast<const bf16x8*>(wrow + kc * 32);
    bf16x8 a0 = *reinterpret_cast<const bf16x8*>(&LA[l15 * pitch + quad * 8 + kc * 32]);
    bf16x8 a1 = *reinterpret_cast<const bf16x8*>(&LA[(16 + l15) * pitch + quad * 8 + kc * 32]);
    acc0 = __builtin_amdgcn_mfma_f32_16x16x32_bf16(a0, bfrag, acc0, 0, 0, 0);
    acc1 = __builtin_amdgcn_mfma_f32_16x16x32_bf16(a1, bfrag, acc1, 0, 0, 0);
  }
  const float bv = bias[nn];
  const int row = b * 256 + nn;
  unsigned short* xo = Xout + row * Lpout;
  float* yo = Yl + row * 128;
#pragma unroll
  for (int r = 0; r < 4; ++r) {
    int m = m0 + quad * 4 + r;
    if (m < Lout) { float v = acc0[r] + bv; yo[m] = v; if (writeX) xo[m] = f2bf(v); }
    int m2 = m0 + 16 + quad * 4 + r;
    if (m2 < Lout) { float v = acc1[r] + bv; yo[m2] = v; if (writeX) xo[m2] = f2bf(v); }
  }
}

// ---- one serial stage = two independent sub-convs of the same input.
template<int KWA, int KWB, int CS>
__global__ __launch_bounds__(256) void pair_kernel(
    const unsigned short* __restrict__ Xin, unsigned short* __restrict__ Xout,
    const unsigned short* __restrict__ WA, const unsigned short* __restrict__ WB,
    const float* __restrict__ biasA, const float* __restrict__ biasB,
    float* __restrict__ YA, float* __restrict__ YB,
    int Lpin, int LoutA, int LoutB, int Lpout)
{
  __shared__ unsigned short LA[32 * (256 * KWB + 8)];
  const int tid = threadIdx.x, b = blockIdx.z, m0 = blockIdx.x * 32;
  const int ysub = blockIdx.y >> 2, n0 = (blockIdx.y & 3) * 64;
  if (ysub == 0)
    conv_sub<KWA, CS>(Xin, (unsigned short*)0, WA, biasA, YA, LA,
                      Lpin, LoutA, 0, b, m0, n0, tid, false);
  else
    conv_sub<KWB, CS>(Xin, Xout, WB, biasB, YB, LA,
                      Lpin, LoutB, Lpout, b, m0, n0, tid, true);
}

__global__ __launch_bounds__(256) void single_kernel(
    const unsigned short* __restrict__ Xin, unsigned short* __restrict__ Xout,
    const unsigned short* __restrict__ WP, const float* __restrict__ bias,
    float* __restrict__ Yl, int Lpin, int Lout, int Lpout)
{
  __shared__ unsigned short LA[32 * 520];
  conv_sub<2, 1>(Xin, Xout, WP, bias, Yl, LA, Lpin, Lout, Lpout,
                 blockIdx.z, blockIdx.x * 32, blockIdx.y * 64, threadIdx.x, true);
}

// ---- assemble (unchanged from round 3).
__global__ __launch_bounds__(256) void assemble_kernel(
    float* __restrict__ out, const float* __restrict__ x,
    const unsigned short* __restrict__ tbl, const float* __restrict__ Y)
{
  __shared__ float S[32 * 129];
  const int blk = blockIdx.x;
  const int tid = threadIdx.x;
  {
    const int m = tid & 127, half = tid >> 7;
#pragma unroll
    for (int lp = 0; lp < 16; ++lp) {
      const int l = lp * 2 + half;
      if (l < 31) {
        const int Lout = (l < 15) ? (127 - l)
                       : (l == 15) ? 56
                       : (l < 23)  ? (71 - l)
                       : (l == 23) ? 24 : (47 - l);
        if (m < Lout) S[l * 129 + m] = Y[(long)l * 524288 + blk * 128 + m];
      } else {
        S[31 * 129 + m] = x[blk * 128 + m];
      }
    }
  }
  __syncthreads();
  const long obase = (long)blk << 14;
#pragma unroll 1
  for (int it = 0; it < 16; ++it) {
    const int flat = it * 256 + tid;
    ushort4v t4 = *reinterpret_cast<const ushort4v*>(tbl + 4 * flat);
    fvec4 v;
#pragma unroll
    for (int jj = 0; jj < 4; ++jj) {
      const unsigned short t = t4[jj];
      const int idx = (t == 0xFFFFu) ? 0 : (int)t;
      const float sv = S[idx];
      v[jj] = (t == 0xFFFFu) ? 0.f : sv;
    }
    *reinterpret_cast<fvec4*>(out + obase + 4 * flat) = v;
  }
}

extern "C" void kernel_launch(void* const* d_in, const int* in_sizes, int n_in,
                              void* d_out, int out_size, void* d_ws, size_t ws_size,
                              hipStream_t stream)
{
  const float* x  = (const float*)d_in[0];
  const float* w2 = (const float*)d_in[1];
  const float* b2 = (const float*)d_in[2];
  const float* w3 = (const float*)d_in[3];
  const float* b3 = (const float*)d_in[4];
  float* out = (float*)d_out;
  unsigned short* ws = (unsigned short*)d_ws;
  unsigned short* tbl = (unsigned short*)((char*)d_ws + TBL_OFF_B);
  unsigned short* cp3 = ws + CP3_OFF_B / 2;
  unsigned short* cp5 = ws + CP5_OFF_B / 2;
  float* beff = (float*)((char*)d_ws + BEFF_OFF_B);
  float* Y = (float*)((char*)d_ws + Y_OFF_B);
  unsigned short* wp2 = ws;
  unsigned short* wp3 = ws + WP3_OFF;

  prep_kernel<<<8320, 256, 0, stream>>>(w2, w3, x, ws);
  wt_kernel<<<496, 256, 0, stream>>>(w2, w3, ws);
  tbl_kernel<<<64, 256, 0, stream>>>(tbl);
  beff_kernel<<<15, 256, 0, stream>>>(w2, b2, b3, beff);
  compose_kernel<<<272, 256, 0, stream>>>(ws);

  long xcur = X0_OFF; int Pcur = 128, Lcur = 128;
  long xnext = xcur + 524288 + 64;

  // group A: pairs (0,1)..(12,13)
  for (int s = 0; s < 7; ++s) {
    const int jA = 2 * s;
    const int LoutA = Lcur - 1, LoutB = Lcur - 2;
    const int Pout = (LoutB + 7) & ~7;
    dim3 grid((LoutA + 31) / 32, 8, 16);
    pair_kernel<2, 3, 1><<<grid, 256, 0, stream>>>(
        ws + xcur, ws + xnext, wp2 + (long)jA * 131072, cp3 + (long)s * 196608,
        b2 + jA * 256, beff + s * 256,
        Y + (long)jA * 524288, Y + (long)(jA + 1) * 524288,
        Pcur, LoutA, LoutB, Pout);
    xcur = xnext; xnext += (long)16 * 256 * Pout + 64; Pcur = Pout; Lcur = LoutB;
  }
  // single layer 14
  {
    const int Lout = Lcur - 1, Pout = (Lout + 7) & ~7;
    single_kernel<<<dim3((Lout + 31) / 32, 4, 16), 256, 0, stream>>>(
        ws + xcur, ws + xnext, wp2 + (long)14 * 131072, b2 + 14 * 256,
        Y + (long)14 * 524288, Pcur, Lout, Pout);
    xcur = xnext; xnext += (long)16 * 256 * Pout + 64; Pcur = Pout; Lcur = Lout;
  }
  // stage (15,16): k3s2 + composed k5s2
  {
    const int LoutA = (Lcur - 3) / 2 + 1, LoutB = LoutA - 1;
    const int Pout = (LoutB + 7) & ~7;
    dim3 grid((LoutA + 31) / 32, 8, 16);
    pair_kernel<3, 5, 2><<<grid, 256, 0, stream>>>(
        ws + xcur, ws + xnext, wp3, cp5,
        b3, beff + 13 * 256,
        Y + (long)15 * 524288, Y + (long)16 * 524288,
        Pcur, LoutA, LoutB, Pout);
    xcur = xnext; xnext += (long)16 * 256 * Pout + 64; Pcur = Pout; Lcur = LoutB;
  }
  // group B pairs (17,18)(19,20)(21,22)
  for (int s = 0; s < 3; ++s) {
    const int jA = 17 + 2 * s, w2i = 16 + 2 * s, unit = 7 + s;
    const int LoutA = Lcur - 1, LoutB = Lcur - 2;
    const int Pout = (LoutB + 7) & ~7;
    dim3 grid((LoutA + 31) / 32, 8, 16);
    pair_kernel<2, 3, 1><<<grid, 256, 0, stream>>>(
        ws + xcur, ws + xnext, wp2 + (long)w2i * 131072, cp3 + (long)unit * 196608,
        b2 + w2i * 256, beff + unit * 256,
        Y + (long)jA * 524288, Y + (long)(jA + 1) * 524288,
        Pcur, LoutA, LoutB, Pout);
    xcur = xnext; xnext += (long)16 * 256 * Pout + 64; Pcur = Pout; Lcur = LoutB;
  }
  // stage (23,24)
  {
    const int LoutA = (Lcur - 3) / 2 + 1, LoutB = LoutA - 1;
    const int Pout = (LoutB + 7) & ~7;
    dim3 grid((LoutA + 31) / 32, 8, 16);
    pair_kernel<3, 5, 2><<<grid, 256, 0, stream>>>(
        ws + xcur, ws + xnext, wp3 + 196608, cp5 + 327680,
        b3 + 256, beff + 14 * 256,
        Y + (long)23 * 524288, Y + (long)24 * 524288,
        Pcur, LoutA, LoutB, Pout);
    xcur = xnext; xnext += (long)16 * 256 * Pout + 64; Pcur = Pout; Lcur = LoutB;
  }
  // group C pairs (25,26)(27,28)(29,30)
  for (int s = 0; s < 3; ++s) {
    const int jA = 25 + 2 * s, w2i = 23 + 2 * s, unit = 10 + s;
    const int LoutA = Lcur - 1, LoutB = Lcur - 2;
    const int Pout = (LoutB + 7) & ~7;
    dim3 grid((LoutA + 31) / 32, 8, 16);
    pair_kernel<2, 3, 1><<<grid, 256, 0, stream>>>(
        ws + xcur, ws + xnext, wp2 + (long)w2i * 131072, cp3 + (long)unit * 196608,
        b2 + w2i * 256, beff + unit * 256,
        Y + (long)jA * 524288, Y + (long)(jA + 1) * 524288,
        Pcur, LoutA, LoutB, Pout);
    xcur = xnext; xnext += (long)16 * 256 * Pout + 64; Pcur = Pout; Lcur = LoutB;
  }

  assemble_kernel<<<4096, 256, 0, stream>>>(out, x, tbl, Y);
}